// Round 3
// baseline (198.010 us; speedup 1.0000x reference)
//
#include <hip/hip_runtime.h>

#define S_LEN 2048
#define D_MODEL 512

typedef __attribute__((ext_vector_type(8))) short s8v;   // 8 x bf16 (4 VGPRs) MFMA A/B frag
typedef __attribute__((ext_vector_type(4))) float f4v;   // MFMA C/D frag
typedef __attribute__((ext_vector_type(4))) short s4v;
typedef __attribute__((ext_vector_type(4))) int   i4v;
typedef __attribute__((ext_vector_type(2))) int   i2v;

#define MFMA __builtin_amdgcn_mfma_f32_16x16x32_bf16

__device__ inline short f2bf(float x) {            // fp32 -> bf16 RNE
    union { float f; unsigned u; } v; v.f = x;
    unsigned r = v.u + 0x7fffu + ((v.u >> 16) & 1u);
    return (short)(r >> 16);
}
__device__ inline unsigned pack_bf2_trunc(float a, float b) { // truncating pack: 3 inst
    unsigned ua = __builtin_bit_cast(unsigned, a);
    unsigned ub = __builtin_bit_cast(unsigned, b);
    return (ua >> 16) | (ub & 0xffff0000u);
}

template <int C>
__device__ inline float dppf(float x) {            // DPP permute within 16-lane row
    int i = __builtin_bit_cast(int, x);
    i = __builtin_amdgcn_update_dpp(0, i, C, 0xF, 0xF, true);
    return __builtin_bit_cast(float, i);
}
__device__ inline float rowsum16(float x) {
    x += dppf<0xB1>(x);
    x += dppf<0x4E>(x);
    x += dppf<0x141>(x);
    x += dppf<0x140>(x);
    return x;
}

// async global->LDS, 16B per lane. LDS dest is wave-uniform base + lane*16
// (per-lane pointers computed as base + tid*16 satisfy this layout).
typedef const __attribute__((address_space(1))) void* gptr_t;
typedef __attribute__((address_space(3))) void* sptr_t;
__device__ inline void gload16(const void* g, void* s) {
    __builtin_amdgcn_global_load_lds((gptr_t)g, (sptr_t)s, 16, 0, 0);
}

// ---------------- prep: transpose weights to bf16 (LDS-tiled, coalesced) ----------------
__global__ __launch_bounds__(256) void prep_kernel(
    const float* __restrict__ Wo, const float* __restrict__ Wq,
    const float* __restrict__ Wk, const float* __restrict__ Wv,
    short* __restrict__ WoT, short* __restrict__ WqT,
    short* __restrict__ WkT, short* __restrict__ WvT)
{
    if (blockIdx.x < 64) {
        __shared__ short t[64 * 65];
        const int bi = (blockIdx.x >> 3) * 64;   // input-dim base (i)
        const int bj = (blockIdx.x & 7) * 64;    // output-dim base (o)
        const int c = threadIdx.x & 63, rr = threadIdx.x >> 6;
#pragma unroll
        for (int r = 0; r < 16; r++) {
            int i = r * 4 + rr;
            t[c * 65 + i] = f2bf(Wo[(size_t)(bi + i) * 512 + bj + c]);  // coalesced read
        }
        __syncthreads();
#pragma unroll
        for (int r = 0; r < 16; r++) {
            int o = r * 4 + rr;
            WoT[(size_t)(bj + o) * 512 + bi + c] = t[o * 65 + c];       // coalesced write
        }
    } else {
        for (int j = threadIdx.x; j < 12288; j += 256) {
            int w = j >> 12, r = j & 4095;
            int e = r >> 6, d = r & 63;
            const float* W = (w == 0) ? Wq : (w == 1) ? Wk : Wv;
            short* WT = (w == 0) ? WqT : (w == 1) ? WkT : WvT;
            WT[r] = f2bf(W[d * 64 + e]);         // WT[e][d], tiny
        }
    }
}

// ---------------- projections: qp/kp [b][h][s][64], vpT [b][h][e][s] ----------------
// For q/k the MFMA n-axis is relabeled e = 4*l + nt so the 4 nt-registers pack
// into one 8B store (e stays true-order in memory).
__global__ __launch_bounds__(256) void proj_kernel(
    const float* __restrict__ q, const float* __restrict__ k, const float* __restrict__ v,
    const float* __restrict__ bq, const float* __restrict__ bk, const float* __restrict__ bv,
    const short* __restrict__ WqT, const short* __restrict__ WkT, const short* __restrict__ WvT,
    short* __restrict__ qp, short* __restrict__ kp, short* __restrict__ vpT)
{
    const int t = blockIdx.z >> 2;     // 0:q 1:k 2:v
    const int b = blockIdx.z & 3;
    const int h = blockIdx.y;
    const int qt = blockIdx.x;         // 16 row-tiles of 128
    const int w = threadIdx.x >> 6, lane = threadIdx.x & 63;
    const int l = lane & 15, qd = lane >> 4;

    const float* X    = (t == 0) ? q   : (t == 1) ? k   : v;
    const float* bias = (t == 0) ? bq  : (t == 1) ? bk  : bv;
    const short* WT   = (t == 0) ? WqT : (t == 1) ? WkT : WvT;

    const int s0 = qt * 128 + w * 32;

    // A frags direct from global fp32, converted
    s8v a[2][2];
#pragma unroll
    for (int mt = 0; mt < 2; mt++)
#pragma unroll
        for (int kk = 0; kk < 2; kk++) {
            const float* p = X + (size_t)(b * S_LEN + s0 + mt * 16 + l) * 512 + h * 64 + kk * 32 + qd * 8;
            f4v x0 = *(const f4v*)p;
            f4v x1 = *(const f4v*)(p + 4);
            s8v fr;
            fr[0] = f2bf(x0[0]); fr[1] = f2bf(x0[1]); fr[2] = f2bf(x0[2]); fr[3] = f2bf(x0[3]);
            fr[4] = f2bf(x1[0]); fr[5] = f2bf(x1[1]); fr[6] = f2bf(x1[2]); fr[7] = f2bf(x1[3]);
            a[mt][kk] = fr;
        }
    // B frags: q/k use e = 4*l + nt, v uses e = nt*16 + l
    s8v wf[4][2];
#pragma unroll
    for (int nt = 0; nt < 4; nt++) {
        int wrow = (t < 2) ? (4 * l + nt) : (nt * 16 + l);
#pragma unroll
        for (int kk = 0; kk < 2; kk++)
            wf[nt][kk] = *(const s8v*)(WT + wrow * 64 + kk * 32 + qd * 8);
    }

    const f4v fz = {0.f, 0.f, 0.f, 0.f};
    f4v acc[2][4];
#pragma unroll
    for (int mt = 0; mt < 2; mt++)
#pragma unroll
        for (int nt = 0; nt < 4; nt++) acc[mt][nt] = fz;

#pragma unroll
    for (int kk = 0; kk < 2; kk++)
#pragma unroll
        for (int nt = 0; nt < 4; nt++)
#pragma unroll
            for (int mt = 0; mt < 2; mt++)
                acc[mt][nt] = MFMA(a[mt][kk], wf[nt][kk], acc[mt][nt], 0, 0, 0);

    // fold softmax scale * log2(e) into Q so attention uses exp2 directly
    const float SC = 0.125f * 1.442695041f;

    if (t < 2) {
        short* out = (t == 0) ? qp : kp;
        float bbs[4];
#pragma unroll
        for (int nt = 0; nt < 4; nt++) bbs[nt] = bias[4 * l + nt];
#pragma unroll
        for (int mt = 0; mt < 2; mt++)
#pragma unroll
            for (int r = 0; r < 4; r++) {
                int s = s0 + mt * 16 + qd * 4 + r;
                s4v pk;
#pragma unroll
                for (int nt = 0; nt < 4; nt++) {
                    float val = acc[mt][nt][r] + bbs[nt];
                    if (t == 0) val *= SC;
                    pk[nt] = f2bf(val);
                }
                *(s4v*)(out + ((size_t)(b * 8 + h) * S_LEN + s) * 64 + 4 * l) = pk;
            }
    } else {
        // vpT[b][h][e][s]: 4 consecutive s per lane -> 8B packed stores
#pragma unroll
        for (int nt = 0; nt < 4; nt++) {
            float bb = bias[nt * 16 + l];
            int e = nt * 16 + l;
#pragma unroll
            for (int mt = 0; mt < 2; mt++) {
                s4v pk;
#pragma unroll
                for (int r = 0; r < 4; r++) pk[r] = f2bf(acc[mt][nt][r] + bb);
                *(s4v*)(vpT + ((size_t)(b * 8 + h) * 64 + e) * S_LEN + s0 + mt * 16 + qd * 4) = pk;
            }
        }
    }
}

// ---------------- repack K/V into MFMA-fragment order ----------------
// Pays the 16-line gather cost ONCE per tile (vs once per wave-tile in attn).
// kfrag tile [bh][kb]: chunk c = nt*2+kk (8 chunks of 1 KB), lane f = qd*16+l:
//   kfrag[...][c][f] = kp[bh][kb*64 + 4l+nt][kk*32+qd*8 .. +8]
// vfrag identical indexing from vpT (rows are e, cols are keys).
__global__ __launch_bounds__(128) void repack_kernel(
    const short* __restrict__ kp, const short* __restrict__ vpT,
    short* __restrict__ kfrag, short* __restrict__ vfrag)
{
    const int kb = blockIdx.x, h = blockIdx.y, b = blockIdx.z;
    const int bh = b * 8 + h;
    const int half = threadIdx.x >> 6, f = threadIdx.x & 63;
    const int l = f & 15, qd = f >> 4;
    const size_t slab = (size_t)bh * S_LEN * 64;
    const size_t obase = ((size_t)bh * 32 + kb) * 4096;
    if (half == 0) {
        const short* src = kp + slab;
#pragma unroll
        for (int c = 0; c < 8; c++) {
            int nt = c >> 1, kk = c & 1;
            s8v x = *(const s8v*)(src + (size_t)(kb * 64 + 4 * l + nt) * 64 + kk * 32 + qd * 8);
            *(s8v*)(kfrag + obase + c * 512 + f * 8) = x;    // coalesced 1KB store
        }
    } else {
        const short* src = vpT + slab;
#pragma unroll
        for (int c = 0; c < 8; c++) {
            int ne = c >> 1, kk = c & 1;
            s8v x = *(const s8v*)(src + (size_t)(4 * l + ne) * S_LEN + kb * 64 + kk * 32 + qd * 8);
            *(s8v*)(vfrag + obase + c * 512 + f * 8) = x;
        }
    }
}

// ---------------- flash attention v7: 64 q-rows per wave ------------------------------
// The attn loop is LDS-bandwidth-bound (K/V/P LDS traffic ~10 cyc per q-row vs
// 4.8 MFMA cyc; bank conflicts are at the conflict-free minimum already). Fix:
// 64 q-rows per wave (4 m-tiles) so the 16 K/V b128 reads per iter serve 2x the
// MFMA work -> ~30% fewer LDS cycles per q-row. 2 waves/block, grid stays 512.
// S-tiles processed in two mt-groups to cap live VGPRs (~200). Second grid half
// flips b (b^=3) so each CU pairs a heavy-vlen batch with a light one.
__global__ __launch_bounds__(128, 2) void attn_kernel(
    const short* __restrict__ qp, const short* __restrict__ kfrag,
    const short* __restrict__ vfrag,
    const int* __restrict__ valid_lens, short* __restrict__ ctx)
{
    __shared__ alignas(16) short kbuf[2][4096];   // 8 KB K tile, frag order, dbuf
    __shared__ alignas(16) short vbuf[2][4096];   // 8 KB V tile
    __shared__ alignas(16) short lP[2][64 * 72];  // per-wave P scratch, stride 72

    const int gid = blockIdx.x;
    const int h  = gid & 7;            // gid%8 -> XCD heuristic for K/V L2 locality
    int b        = (gid >> 3) & 3;
    const int qt = gid >> 5;           // 0..15, 128 rows per block
    b ^= 3 * ((gid >> 8) & 1);         // pair heavy/light vlen batches per CU
    const int w = threadIdx.x >> 6, lane = threadIdx.x & 63;
    const int l = lane & 15, qd = lane >> 4;
    const int vlen = valid_lens[b];
    const int ntiles = (vlen + 63) >> 6;   // skip fully-masked tiles: exp==0 exactly

    const int bh = b * 8 + h;
    const short* Qs = qp + (size_t)bh * S_LEN * 64;
    const short* Kf = kfrag + (size_t)bh * 32 * 4096;
    const short* Vf = vfrag + (size_t)bh * 32 * 4096;

    const int s0 = qt * 128 + w * 64;
    s8v qf[4][2];
#pragma unroll
    for (int mt = 0; mt < 4; mt++)
#pragma unroll
        for (int kk = 0; kk < 2; kk++)
            qf[mt][kk] = *(const s8v*)(Qs + (size_t)(s0 + mt * 16 + l) * 64 + kk * 32 + qd * 8);

    const f4v fz = {0.f, 0.f, 0.f, 0.f};
    f4v O[4][4];
    float lsum[4][4];
#pragma unroll
    for (int mt = 0; mt < 4; mt++)
#pragma unroll
        for (int r = 0; r < 4; r++) lsum[mt][r] = 0.f;
#pragma unroll
    for (int mt = 0; mt < 4; mt++)
#pragma unroll
        for (int ne = 0; ne < 4; ne++) O[mt][ne] = fz;

    short* lPw = lP[w];
    const int toff = threadIdx.x * 8;  // 16B per thread; per-wave-linear LDS dest

    // prologue: stage tile 0 into buffer 0 (2KB per round, 4 rounds per tensor)
#pragma unroll
    for (int r = 0; r < 4; r++) gload16(Kf + r * 1024 + toff, &kbuf[0][r * 1024 + toff]);
#pragma unroll
    for (int r = 0; r < 4; r++) gload16(Vf + r * 1024 + toff, &vbuf[0][r * 1024 + toff]);
    __syncthreads();   // compiler emits vmcnt(0) drain before s_barrier

    for (int kb = 0; kb < ntiles; kb++) {
        const int cur = kb & 1;
        // issue next-tile prefetch FIRST so it flies under this tile's compute
        if (kb + 1 < ntiles) {
            const short* Ks = Kf + (size_t)(kb + 1) * 4096;
            const short* Vs = Vf + (size_t)(kb + 1) * 4096;
#pragma unroll
            for (int r = 0; r < 4; r++) gload16(Ks + r * 1024 + toff, &kbuf[cur ^ 1][r * 1024 + toff]);
#pragma unroll
            for (int r = 0; r < 4; r++) gload16(Vs + r * 1024 + toff, &vbuf[cur ^ 1][r * 1024 + toff]);
        }

        // K fragments from LDS: contiguous 1KB per chunk, conflict-free
        const short* Kb = &kbuf[cur][lane * 8];
        s8v kf[4][2];
#pragma unroll
        for (int nt = 0; nt < 4; nt++)
#pragma unroll
            for (int kk = 0; kk < 2; kk++)
                kf[nt][kk] = *(const s8v*)(Kb + (nt * 2 + kk) * 512);

        const bool mask_on = (kb == ntiles - 1) && (vlen & 63);
        const int rem = vlen - kb * 64;

        // two mt-groups of 2 m-tiles each: halves the live S-register footprint and
        // lets group-1 MFMAs overlap group-0 softmax VALU.
#pragma unroll
        for (int g = 0; g < 2; g++) {
            f4v sf[2][4];
#pragma unroll
            for (int mt = 0; mt < 2; mt++)
#pragma unroll
                for (int nt = 0; nt < 4; nt++) sf[mt][nt] = fz;
            __builtin_amdgcn_s_setprio(1);
#pragma unroll
            for (int nt = 0; nt < 4; nt++)
#pragma unroll
                for (int mt = 0; mt < 2; mt++) {
                    sf[mt][nt] = MFMA(qf[g * 2 + mt][0], kf[nt][0], sf[mt][nt], 0, 0, 0);
                    sf[mt][nt] = MFMA(qf[g * 2 + mt][1], kf[nt][1], sf[mt][nt], 0, 0, 0);
                }
            __builtin_amdgcn_s_setprio(0);

            // boundary-tile key mask (key at (nt,l) = kb*64 + 4*l + nt)
            if (mask_on) {
#pragma unroll
                for (int nt = 0; nt < 4; nt++)
                    if (4 * l + nt >= rem) {
#pragma unroll
                        for (int mt = 0; mt < 2; mt++)
#pragma unroll
                            for (int r = 0; r < 4; r++) sf[mt][nt][r] = -1e30f;
                    }
            }

            // softmax, no max subtraction; truncating bf16 pack; one ds_write_b64/row-reg
#pragma unroll
            for (int mt = 0; mt < 2; mt++)
#pragma unroll
                for (int r = 0; r < 4; r++) {
                    float p0 = __builtin_amdgcn_exp2f(sf[mt][0][r]);
                    float p1 = __builtin_amdgcn_exp2f(sf[mt][1][r]);
                    float p2 = __builtin_amdgcn_exp2f(sf[mt][2][r]);
                    float p3 = __builtin_amdgcn_exp2f(sf[mt][3][r]);
                    lsum[g * 2 + mt][r] += (p0 + p1) + (p2 + p3);
                    i2v pk;
                    pk[0] = (int)pack_bf2_trunc(p0, p1);
                    pk[1] = (int)pack_bf2_trunc(p2, p3);
                    *(i2v*)(lPw + ((g * 2 + mt) * 16 + qd * 4 + r) * 72 + 4 * l) = pk;
                }
        }

        // V fragments
        const short* Vb = &vbuf[cur][lane * 8];
        s8v vf[4][2];
#pragma unroll
        for (int ne = 0; ne < 4; ne++)
#pragma unroll
            for (int kk = 0; kk < 2; kk++)
                vf[ne][kk] = *(const s8v*)(Vb + (ne * 2 + kk) * 512);

        // O += P V  (A-frags from wave-private LDS; no barrier needed)
        s8v pa[4][2];
#pragma unroll
        for (int mt = 0; mt < 4; mt++)
#pragma unroll
            for (int kk = 0; kk < 2; kk++)
                pa[mt][kk] = *(const s8v*)(lPw + (mt * 16 + l) * 72 + kk * 32 + qd * 8);
        __builtin_amdgcn_s_setprio(1);
#pragma unroll
        for (int ne = 0; ne < 4; ne++)
#pragma unroll
            for (int mt = 0; mt < 4; mt++) {
                O[mt][ne] = MFMA(pa[mt][0], vf[ne][0], O[mt][ne], 0, 0, 0);
                O[mt][ne] = MFMA(pa[mt][1], vf[ne][1], O[mt][ne], 0, 0, 0);
            }
        __builtin_amdgcn_s_setprio(0);

        // all waves done reading buf[cur]; prefetch into buf[cur^1] drained here
        __syncthreads();
    }

    // normalize + write ctx[b][s][h*64 + e] (bf16), packed 8B stores (e = 4*l+ne)
#pragma unroll
    for (int mt = 0; mt < 4; mt++)
#pragma unroll
        for (int r = 0; r < 4; r++) {
            float inv = 1.0f / rowsum16(lsum[mt][r]);
            int s = s0 + mt * 16 + qd * 4 + r;
            s4v pk;
#pragma unroll
            for (int ne = 0; ne < 4; ne++) pk[ne] = f2bf(O[mt][ne][r] * inv);
            *(s4v*)(ctx + ((size_t)(b * S_LEN + s)) * 512 + h * 64 + 4 * l) = pk;
        }
}

// ---------------- output projection: [8192,512] = ctx @ Wo + bo ----------------
__global__ __launch_bounds__(256) void outproj_kernel(
    const short* __restrict__ ctx, const short* __restrict__ WoT,
    const float* __restrict__ bo, float* __restrict__ out)
{
    __shared__ short lB[64 * 520];   // Wo^T tile, padded stride (kills 1024B-stride alias)
    __shared__ short lA[128 * 40];   // A k-slab, padded stride 40 shorts (80B)

    const int rb = blockIdx.x * 128;
    const int nb = blockIdx.y * 64;
    const int w = threadIdx.x >> 6, lane = threadIdx.x & 63;
    const int l = lane & 15, qd = lane >> 4;

    {   // stage B tile once: 64 rows x 512
        int n = threadIdx.x >> 2, c0 = threadIdx.x & 3;
#pragma unroll
        for (int i = 0; i < 16; i++) {
            int g = i * 4 + c0;  // 64 granules of 8 shorts
            i4v x = *(const i4v*)(WoT + (size_t)(nb + n) * 512 + g * 8);
            *(i4v*)(lB + n * 520 + g * 8) = x;
        }
    }
    __syncthreads();

    const f4v fz = {0.f, 0.f, 0.f, 0.f};
    f4v acc[2][4];
#pragma unroll
    for (int mt = 0; mt < 2; mt++)
#pragma unroll
        for (int nt = 0; nt < 4; nt++) acc[mt][nt] = fz;

    for (int ko = 0; ko < 16; ko++) {
        {   // stage A slab 128x32
            int r = threadIdx.x >> 1, hp = threadIdx.x & 1;
            const short* src = ctx + (size_t)(rb + r) * 512 + ko * 32 + hp * 16;
            i4v x0 = *(const i4v*)src;
            i4v x1 = *(const i4v*)(src + 8);
            *(i4v*)(lA + r * 40 + hp * 16) = x0;
            *(i4v*)(lA + r * 40 + hp * 16 + 8) = x1;
        }
        __syncthreads();
        s8v af[2];
#pragma unroll
        for (int mt = 0; mt < 2; mt++)
            af[mt] = *(const s8v*)(lA + (w * 32 + mt * 16 + l) * 40 + qd * 8);
#pragma unroll
        for (int nt = 0; nt < 4; nt++) {
            s8v bfr = *(const s8v*)(lB + (nt * 16 + l) * 520 + ko * 32 + qd * 8);
#pragma unroll
            for (int mt = 0; mt < 2; mt++)
                acc[mt][nt] = MFMA(af[mt], bfr, acc[mt][nt], 0, 0, 0);
        }
        __syncthreads();
    }

#pragma unroll
    for (int nt = 0; nt < 4; nt++) {
        float bias = bo[nb + nt * 16 + l];
#pragma unroll
        for (int mt = 0; mt < 2; mt++)
#pragma unroll
            for (int r = 0; r < 4; r++) {
                int row = rb + w * 32 + mt * 16 + qd * 4 + r;
                out[(size_t)row * 512 + nb + nt * 16 + l] = acc[mt][nt][r] + bias;
            }
    }
}

extern "C" void kernel_launch(void* const* d_in, const int* in_sizes, int n_in,
                              void* d_out, int out_size, void* d_ws, size_t ws_size,
                              hipStream_t stream)
{
    const float* q  = (const float*)d_in[0];
    const float* k  = (const float*)d_in[1];
    const float* v  = (const float*)d_in[2];
    const float* Wq = (const float*)d_in[3];
    const float* bq = (const float*)d_in[4];
    const float* Wk = (const float*)d_in[5];
    const float* bk = (const float*)d_in[6];
    const float* Wv = (const float*)d_in[7];
    const float* bv = (const float*)d_in[8];
    const float* Wo = (const float*)d_in[9];
    const float* bo = (const float*)d_in[10];
    const int*   vl = (const int*)d_in[11];
    float* out = (float*)d_out;

    char* ws = (char*)d_ws;
    const size_t SL = (size_t)4 * 8 * S_LEN * 64 * sizeof(short);  // 8 MiB per tensor
    // Lifetimes (stream-serialized): kp dies after repack, so ctx reuses its slab.
    short* qp    = (short*)(ws);            // proj -> attn
    short* kp    = (short*)(ws + SL);       // proj -> repack (dead after)
    short* ctx   = (short*)(ws + SL);       // attn -> outproj (reuses kp slab)
    short* vpT   = (short*)(ws + 2 * SL);   // proj -> repack
    short* kfrag = (short*)(ws + 3 * SL);   // repack -> attn
    short* vfrag = (short*)(ws + 4 * SL);   // repack -> attn
    short* WoT = (short*)(ws + 5 * SL);
    short* WqT = WoT + 512 * 512;
    short* WkT = WqT + 4096;
    short* WvT = WkT + 4096;

    prep_kernel<<<65, 256, 0, stream>>>(Wo, Wq, Wk, Wv, WoT, WqT, WkT, WvT);
    proj_kernel<<<dim3(16, 8, 12), 256, 0, stream>>>(q, k, v, bq, bk, bv,
                                                     WqT, WkT, WvT, qp, kp, vpT);
    repack_kernel<<<dim3(32, 8, 4), 128, 0, stream>>>(kp, vpT, kfrag, vfrag);
    attn_kernel<<<512, 128, 0, stream>>>(qp, kfrag, vfrag, vl, ctx);
    outproj_kernel<<<dim3(64, 8), 256, 0, stream>>>(ctx, WoT, bo, out);
}

// Round 4
// 180.324 us; speedup vs baseline: 1.0981x; 1.0981x over previous
//
#include <hip/hip_runtime.h>

#define S_LEN 2048
#define D_MODEL 512

typedef __attribute__((ext_vector_type(8))) short s8v;   // 8 x bf16 (4 VGPRs) MFMA A/B frag
typedef __attribute__((ext_vector_type(4))) float f4v;   // MFMA C/D frag
typedef __attribute__((ext_vector_type(4))) short s4v;
typedef __attribute__((ext_vector_type(4))) int   i4v;
typedef __attribute__((ext_vector_type(2))) int   i2v;

#define MFMA __builtin_amdgcn_mfma_f32_16x16x32_bf16

__device__ inline short f2bf(float x) {            // fp32 -> bf16 RNE
    union { float f; unsigned u; } v; v.f = x;
    unsigned r = v.u + 0x7fffu + ((v.u >> 16) & 1u);
    return (short)(r >> 16);
}
__device__ inline unsigned pack_bf2_trunc(float a, float b) { // truncating pack: 3 inst
    unsigned ua = __builtin_bit_cast(unsigned, a);
    unsigned ub = __builtin_bit_cast(unsigned, b);
    return (ua >> 16) | (ub & 0xffff0000u);
}

template <int C>
__device__ inline float dppf(float x) {            // DPP permute within 16-lane row
    int i = __builtin_bit_cast(int, x);
    i = __builtin_amdgcn_update_dpp(0, i, C, 0xF, 0xF, true);
    return __builtin_bit_cast(float, i);
}
__device__ inline float rowsum16(float x) {
    x += dppf<0xB1>(x);
    x += dppf<0x4E>(x);
    x += dppf<0x141>(x);
    x += dppf<0x140>(x);
    return x;
}

// async global->LDS, 16B per lane. LDS dest is wave-uniform base + lane*16
// (per-lane pointers computed as base + tid*16 satisfy this layout).
typedef const __attribute__((address_space(1))) void* gptr_t;
typedef __attribute__((address_space(3))) void* sptr_t;
__device__ inline void gload16(const void* g, void* s) {
    __builtin_amdgcn_global_load_lds((gptr_t)g, (sptr_t)s, 16, 0, 0);
}

// ---------------- prep: transpose weights to bf16 (LDS-tiled, coalesced) ----------------
__global__ __launch_bounds__(256) void prep_kernel(
    const float* __restrict__ Wo, const float* __restrict__ Wq,
    const float* __restrict__ Wk, const float* __restrict__ Wv,
    short* __restrict__ WoT, short* __restrict__ WqT,
    short* __restrict__ WkT, short* __restrict__ WvT)
{
    if (blockIdx.x < 64) {
        __shared__ short t[64 * 65];
        const int bi = (blockIdx.x >> 3) * 64;   // input-dim base (i)
        const int bj = (blockIdx.x & 7) * 64;    // output-dim base (o)
        const int c = threadIdx.x & 63, rr = threadIdx.x >> 6;
#pragma unroll
        for (int r = 0; r < 16; r++) {
            int i = r * 4 + rr;
            t[c * 65 + i] = f2bf(Wo[(size_t)(bi + i) * 512 + bj + c]);  // coalesced read
        }
        __syncthreads();
#pragma unroll
        for (int r = 0; r < 16; r++) {
            int o = r * 4 + rr;
            WoT[(size_t)(bj + o) * 512 + bi + c] = t[o * 65 + c];       // coalesced write
        }
    } else {
        for (int j = threadIdx.x; j < 12288; j += 256) {
            int w = j >> 12, r = j & 4095;
            int e = r >> 6, d = r & 63;
            const float* W = (w == 0) ? Wq : (w == 1) ? Wk : Wv;
            short* WT = (w == 0) ? WqT : (w == 1) ? WkT : WvT;
            WT[r] = f2bf(W[d * 64 + e]);         // WT[e][d], tiny
        }
    }
}

// ---------------- projections: qp/kp [b][h][s][64], vpT [b][h][e][s] ----------------
// For q/k the MFMA n-axis is relabeled e = 4*l + nt so the 4 nt-registers pack
// into one 8B store (e stays true-order in memory).
__global__ __launch_bounds__(256) void proj_kernel(
    const float* __restrict__ q, const float* __restrict__ k, const float* __restrict__ v,
    const float* __restrict__ bq, const float* __restrict__ bk, const float* __restrict__ bv,
    const short* __restrict__ WqT, const short* __restrict__ WkT, const short* __restrict__ WvT,
    short* __restrict__ qp, short* __restrict__ kp, short* __restrict__ vpT)
{
    const int t = blockIdx.z >> 2;     // 0:q 1:k 2:v
    const int b = blockIdx.z & 3;
    const int h = blockIdx.y;
    const int qt = blockIdx.x;         // 16 row-tiles of 128
    const int w = threadIdx.x >> 6, lane = threadIdx.x & 63;
    const int l = lane & 15, qd = lane >> 4;

    const float* X    = (t == 0) ? q   : (t == 1) ? k   : v;
    const float* bias = (t == 0) ? bq  : (t == 1) ? bk  : bv;
    const short* WT   = (t == 0) ? WqT : (t == 1) ? WkT : WvT;

    const int s0 = qt * 128 + w * 32;

    // A frags direct from global fp32, converted
    s8v a[2][2];
#pragma unroll
    for (int mt = 0; mt < 2; mt++)
#pragma unroll
        for (int kk = 0; kk < 2; kk++) {
            const float* p = X + (size_t)(b * S_LEN + s0 + mt * 16 + l) * 512 + h * 64 + kk * 32 + qd * 8;
            f4v x0 = *(const f4v*)p;
            f4v x1 = *(const f4v*)(p + 4);
            s8v fr;
            fr[0] = f2bf(x0[0]); fr[1] = f2bf(x0[1]); fr[2] = f2bf(x0[2]); fr[3] = f2bf(x0[3]);
            fr[4] = f2bf(x1[0]); fr[5] = f2bf(x1[1]); fr[6] = f2bf(x1[2]); fr[7] = f2bf(x1[3]);
            a[mt][kk] = fr;
        }
    // B frags: q/k use e = 4*l + nt, v uses e = nt*16 + l
    s8v wf[4][2];
#pragma unroll
    for (int nt = 0; nt < 4; nt++) {
        int wrow = (t < 2) ? (4 * l + nt) : (nt * 16 + l);
#pragma unroll
        for (int kk = 0; kk < 2; kk++)
            wf[nt][kk] = *(const s8v*)(WT + wrow * 64 + kk * 32 + qd * 8);
    }

    const f4v fz = {0.f, 0.f, 0.f, 0.f};
    f4v acc[2][4];
#pragma unroll
    for (int mt = 0; mt < 2; mt++)
#pragma unroll
        for (int nt = 0; nt < 4; nt++) acc[mt][nt] = fz;

#pragma unroll
    for (int kk = 0; kk < 2; kk++)
#pragma unroll
        for (int nt = 0; nt < 4; nt++)
#pragma unroll
            for (int mt = 0; mt < 2; mt++)
                acc[mt][nt] = MFMA(a[mt][kk], wf[nt][kk], acc[mt][nt], 0, 0, 0);

    // fold softmax scale * log2(e) into Q so attention uses exp2 directly
    const float SC = 0.125f * 1.442695041f;

    if (t < 2) {
        short* out = (t == 0) ? qp : kp;
        float bbs[4];
#pragma unroll
        for (int nt = 0; nt < 4; nt++) bbs[nt] = bias[4 * l + nt];
#pragma unroll
        for (int mt = 0; mt < 2; mt++)
#pragma unroll
            for (int r = 0; r < 4; r++) {
                int s = s0 + mt * 16 + qd * 4 + r;
                s4v pk;
#pragma unroll
                for (int nt = 0; nt < 4; nt++) {
                    float val = acc[mt][nt][r] + bbs[nt];
                    if (t == 0) val *= SC;
                    pk[nt] = f2bf(val);
                }
                *(s4v*)(out + ((size_t)(b * 8 + h) * S_LEN + s) * 64 + 4 * l) = pk;
            }
    } else {
        // vpT[b][h][e][s]: 4 consecutive s per lane -> 8B packed stores
#pragma unroll
        for (int nt = 0; nt < 4; nt++) {
            float bb = bias[nt * 16 + l];
            int e = nt * 16 + l;
#pragma unroll
            for (int mt = 0; mt < 2; mt++) {
                s4v pk;
#pragma unroll
                for (int r = 0; r < 4; r++) pk[r] = f2bf(acc[mt][nt][r] + bb);
                *(s4v*)(vpT + ((size_t)(b * 8 + h) * 64 + e) * S_LEN + s0 + mt * 16 + qd * 4) = pk;
            }
        }
    }
}

// ---------------- repack K/V into MFMA-fragment order ----------------
// Pays the 16-line gather cost ONCE per tile (vs once per wave-tile in attn).
// kfrag tile [bh][kb]: chunk c = nt*2+kk (8 chunks of 1 KB), lane f = qd*16+l:
//   kfrag[...][c][f] = kp[bh][kb*64 + 4l+nt][kk*32+qd*8 .. +8]
// vfrag identical indexing from vpT (rows are e, cols are keys).
__global__ __launch_bounds__(128) void repack_kernel(
    const short* __restrict__ kp, const short* __restrict__ vpT,
    short* __restrict__ kfrag, short* __restrict__ vfrag)
{
    const int kb = blockIdx.x, h = blockIdx.y, b = blockIdx.z;
    const int bh = b * 8 + h;
    const int half = threadIdx.x >> 6, f = threadIdx.x & 63;
    const int l = f & 15, qd = f >> 4;
    const size_t slab = (size_t)bh * S_LEN * 64;
    const size_t obase = ((size_t)bh * 32 + kb) * 4096;
    if (half == 0) {
        const short* src = kp + slab;
#pragma unroll
        for (int c = 0; c < 8; c++) {
            int nt = c >> 1, kk = c & 1;
            s8v x = *(const s8v*)(src + (size_t)(kb * 64 + 4 * l + nt) * 64 + kk * 32 + qd * 8);
            *(s8v*)(kfrag + obase + c * 512 + f * 8) = x;    // coalesced 1KB store
        }
    } else {
        const short* src = vpT + slab;
#pragma unroll
        for (int c = 0; c < 8; c++) {
            int ne = c >> 1, kk = c & 1;
            s8v x = *(const s8v*)(src + (size_t)(4 * l + ne) * S_LEN + kb * 64 + kk * 32 + qd * 8);
            *(s8v*)(vfrag + obase + c * 512 + f * 8) = x;
        }
    }
}

// ---------------- flash attention v8: v6 structure + vlen pairing + setprio -----------
// v6 (4 waves/block, LDS-staged K/V, dbuf) measured 42us; counters showed no pipe
// >50% busy -> latency/imbalance-bound. Dominant term: blocks gid and gid+256 share
// a CU and had the SAME batch b -> CUs serving the max-vlen batch did 2x average
// work. Fix: flip b^=3 for the second grid half so each CU pairs batches (b, b^3)
// -> per-CU work ~ (v0+v3) or (v1+v2) instead of 2*v_b. Plus T5 setprio around
// MFMA clusters (waves in a block reach MFMA at different phases).
__global__ __launch_bounds__(256, 3) void attn_kernel(
    const short* __restrict__ qp, const short* __restrict__ kfrag,
    const short* __restrict__ vfrag,
    const int* __restrict__ valid_lens, short* __restrict__ ctx)
{
    __shared__ alignas(16) short kbuf[2][4096];   // 8 KB K tile, frag order, dbuf
    __shared__ alignas(16) short vbuf[2][4096];   // 8 KB V tile
    __shared__ alignas(16) short lP[4][32 * 72];  // per-wave P scratch, stride 72

    const int gid = blockIdx.x;
    const int h  = gid & 7;            // gid%8 -> XCD heuristic for K/V L2 locality
    int b        = (gid >> 3) & 3;
    const int qt = gid >> 5;           // 0..15, 128 rows per block
    b ^= 3 * ((gid >> 8) & 1);         // pair (b, b^3) batches on each CU: vlen balance
    const int w = threadIdx.x >> 6, lane = threadIdx.x & 63;
    const int l = lane & 15, qd = lane >> 4;
    const int vlen = valid_lens[b];
    const int ntiles = (vlen + 63) >> 6;   // skip fully-masked tiles: exp==0 exactly

    const int bh = b * 8 + h;
    const short* Qs = qp + (size_t)bh * S_LEN * 64;
    const short* Kf = kfrag + (size_t)bh * 32 * 4096;
    const short* Vf = vfrag + (size_t)bh * 32 * 4096;

    const int s0 = qt * 128 + w * 32;
    s8v qf[2][2];
#pragma unroll
    for (int mt = 0; mt < 2; mt++)
#pragma unroll
        for (int kk = 0; kk < 2; kk++)
            qf[mt][kk] = *(const s8v*)(Qs + (size_t)(s0 + mt * 16 + l) * 64 + kk * 32 + qd * 8);

    const f4v fz = {0.f, 0.f, 0.f, 0.f};
    f4v O[2][4];
    float lsum[2][4];
#pragma unroll
    for (int mt = 0; mt < 2; mt++)
#pragma unroll
        for (int r = 0; r < 4; r++) lsum[mt][r] = 0.f;
#pragma unroll
    for (int mt = 0; mt < 2; mt++)
#pragma unroll
        for (int ne = 0; ne < 4; ne++) O[mt][ne] = fz;

    short* lPw = lP[w];
    const int toff = threadIdx.x * 8;  // 16B per thread; per-wave-linear LDS dest

    // prologue: stage tile 0 into buffer 0 (4KB per round, 2 rounds per tensor)
    gload16(Kf + toff,        &kbuf[0][toff]);
    gload16(Kf + 2048 + toff, &kbuf[0][2048 + toff]);
    gload16(Vf + toff,        &vbuf[0][toff]);
    gload16(Vf + 2048 + toff, &vbuf[0][2048 + toff]);
    __syncthreads();   // compiler emits vmcnt(0) drain before s_barrier

    for (int kb = 0; kb < ntiles; kb++) {
        const int cur = kb & 1;
        // issue next-tile prefetch FIRST so it flies under this tile's compute
        if (kb + 1 < ntiles) {
            const short* Ks = Kf + (size_t)(kb + 1) * 4096;
            const short* Vs = Vf + (size_t)(kb + 1) * 4096;
            gload16(Ks + toff,        &kbuf[cur ^ 1][toff]);
            gload16(Ks + 2048 + toff, &kbuf[cur ^ 1][2048 + toff]);
            gload16(Vs + toff,        &vbuf[cur ^ 1][toff]);
            gload16(Vs + 2048 + toff, &vbuf[cur ^ 1][2048 + toff]);
        }

        // K fragments from LDS: contiguous 1KB per chunk, conflict-free
        const short* Kb = &kbuf[cur][lane * 8];
        s8v kf[4][2];
#pragma unroll
        for (int nt = 0; nt < 4; nt++)
#pragma unroll
            for (int kk = 0; kk < 2; kk++)
                kf[nt][kk] = *(const s8v*)(Kb + (nt * 2 + kk) * 512);

        f4v sf[2][4];
#pragma unroll
        for (int mt = 0; mt < 2; mt++)
#pragma unroll
            for (int nt = 0; nt < 4; nt++) sf[mt][nt] = fz;
        __builtin_amdgcn_s_setprio(1);
#pragma unroll
        for (int nt = 0; nt < 4; nt++)
#pragma unroll
            for (int mt = 0; mt < 2; mt++) {
                sf[mt][nt] = MFMA(qf[mt][0], kf[nt][0], sf[mt][nt], 0, 0, 0);
                sf[mt][nt] = MFMA(qf[mt][1], kf[nt][1], sf[mt][nt], 0, 0, 0);
            }
        __builtin_amdgcn_s_setprio(0);

        // V fragments (issued here so QK+softmax covers their latency)
        const short* Vb = &vbuf[cur][lane * 8];
        s8v vf[4][2];
#pragma unroll
        for (int ne = 0; ne < 4; ne++)
#pragma unroll
            for (int kk = 0; kk < 2; kk++)
                vf[ne][kk] = *(const s8v*)(Vb + (ne * 2 + kk) * 512);

        // boundary-tile key mask (key at (nt,l) = kb*64 + 4*l + nt)
        if (kb == ntiles - 1 && (vlen & 63)) {
            int rem = vlen - kb * 64;
#pragma unroll
            for (int nt = 0; nt < 4; nt++)
                if (4 * l + nt >= rem) {
#pragma unroll
                    for (int mt = 0; mt < 2; mt++)
#pragma unroll
                        for (int r = 0; r < 4; r++) sf[mt][nt][r] = -1e30f;
                }
        }

        // softmax, no max subtraction; truncating bf16 pack; one ds_write_b64/row-reg
#pragma unroll
        for (int mt = 0; mt < 2; mt++)
#pragma unroll
            for (int r = 0; r < 4; r++) {
                float p0 = __builtin_amdgcn_exp2f(sf[mt][0][r]);
                float p1 = __builtin_amdgcn_exp2f(sf[mt][1][r]);
                float p2 = __builtin_amdgcn_exp2f(sf[mt][2][r]);
                float p3 = __builtin_amdgcn_exp2f(sf[mt][3][r]);
                lsum[mt][r] += (p0 + p1) + (p2 + p3);
                i2v pk;
                pk[0] = (int)pack_bf2_trunc(p0, p1);
                pk[1] = (int)pack_bf2_trunc(p2, p3);
                *(i2v*)(lPw + (mt * 16 + qd * 4 + r) * 72 + 4 * l) = pk;
            }

        // O += P V  (A-frags from wave-private LDS; no barrier needed)
        s8v pa[2][2];
#pragma unroll
        for (int mt = 0; mt < 2; mt++)
#pragma unroll
            for (int kk = 0; kk < 2; kk++)
                pa[mt][kk] = *(const s8v*)(lPw + (mt * 16 + l) * 72 + kk * 32 + qd * 8);
        __builtin_amdgcn_s_setprio(1);
#pragma unroll
        for (int ne = 0; ne < 4; ne++)
#pragma unroll
            for (int mt = 0; mt < 2; mt++) {
                O[mt][ne] = MFMA(pa[mt][0], vf[ne][0], O[mt][ne], 0, 0, 0);
                O[mt][ne] = MFMA(pa[mt][1], vf[ne][1], O[mt][ne], 0, 0, 0);
            }
        __builtin_amdgcn_s_setprio(0);

        // all waves done reading buf[cur]; prefetch into buf[cur^1] drained here
        __syncthreads();
    }

    // normalize + write ctx[b][s][h*64 + e] (bf16), packed 8B stores (e = 4*l+ne)
#pragma unroll
    for (int mt = 0; mt < 2; mt++)
#pragma unroll
        for (int r = 0; r < 4; r++) {
            float inv = 1.0f / rowsum16(lsum[mt][r]);
            int s = s0 + mt * 16 + qd * 4 + r;
            s4v pk;
#pragma unroll
            for (int ne = 0; ne < 4; ne++) pk[ne] = f2bf(O[mt][ne][r] * inv);
            *(s4v*)(ctx + ((size_t)(b * S_LEN + s)) * 512 + h * 64 + 4 * l) = pk;
        }
}

// ---------------- output projection: [8192,512] = ctx @ Wo + bo ----------------
__global__ __launch_bounds__(256) void outproj_kernel(
    const short* __restrict__ ctx, const short* __restrict__ WoT,
    const float* __restrict__ bo, float* __restrict__ out)
{
    __shared__ short lB[64 * 520];   // Wo^T tile, padded stride (kills 1024B-stride alias)
    __shared__ short lA[128 * 40];   // A k-slab, padded stride 40 shorts (80B)

    const int rb = blockIdx.x * 128;
    const int nb = blockIdx.y * 64;
    const int w = threadIdx.x >> 6, lane = threadIdx.x & 63;
    const int l = lane & 15, qd = lane >> 4;

    {   // stage B tile once: 64 rows x 512
        int n = threadIdx.x >> 2, c0 = threadIdx.x & 3;
#pragma unroll
        for (int i = 0; i < 16; i++) {
            int g = i * 4 + c0;  // 64 granules of 8 shorts
            i4v x = *(const i4v*)(WoT + (size_t)(nb + n) * 512 + g * 8);
            *(i4v*)(lB + n * 520 + g * 8) = x;
        }
    }
    __syncthreads();

    const f4v fz = {0.f, 0.f, 0.f, 0.f};
    f4v acc[2][4];
#pragma unroll
    for (int mt = 0; mt < 2; mt++)
#pragma unroll
        for (int nt = 0; nt < 4; nt++) acc[mt][nt] = fz;

    for (int ko = 0; ko < 16; ko++) {
        {   // stage A slab 128x32
            int r = threadIdx.x >> 1, hp = threadIdx.x & 1;
            const short* src = ctx + (size_t)(rb + r) * 512 + ko * 32 + hp * 16;
            i4v x0 = *(const i4v*)src;
            i4v x1 = *(const i4v*)(src + 8);
            *(i4v*)(lA + r * 40 + hp * 16) = x0;
            *(i4v*)(lA + r * 40 + hp * 16 + 8) = x1;
        }
        __syncthreads();
        s8v af[2];
#pragma unroll
        for (int mt = 0; mt < 2; mt++)
            af[mt] = *(const s8v*)(lA + (w * 32 + mt * 16 + l) * 40 + qd * 8);
#pragma unroll
        for (int nt = 0; nt < 4; nt++) {
            s8v bfr = *(const s8v*)(lB + (nt * 16 + l) * 520 + ko * 32 + qd * 8);
#pragma unroll
            for (int mt = 0; mt < 2; mt++)
                acc[mt][nt] = MFMA(af[mt], bfr, acc[mt][nt], 0, 0, 0);
        }
        __syncthreads();
    }

#pragma unroll
    for (int nt = 0; nt < 4; nt++) {
        float bias = bo[nb + nt * 16 + l];
#pragma unroll
        for (int mt = 0; mt < 2; mt++)
#pragma unroll
            for (int r = 0; r < 4; r++) {
                int row = rb + w * 32 + mt * 16 + qd * 4 + r;
                out[(size_t)row * 512 + nb + nt * 16 + l] = acc[mt][nt][r] + bias;
            }
    }
}

extern "C" void kernel_launch(void* const* d_in, const int* in_sizes, int n_in,
                              void* d_out, int out_size, void* d_ws, size_t ws_size,
                              hipStream_t stream)
{
    const float* q  = (const float*)d_in[0];
    const float* k  = (const float*)d_in[1];
    const float* v  = (const float*)d_in[2];
    const float* Wq = (const float*)d_in[3];
    const float* bq = (const float*)d_in[4];
    const float* Wk = (const float*)d_in[5];
    const float* bk = (const float*)d_in[6];
    const float* Wv = (const float*)d_in[7];
    const float* bv = (const float*)d_in[8];
    const float* Wo = (const float*)d_in[9];
    const float* bo = (const float*)d_in[10];
    const int*   vl = (const int*)d_in[11];
    float* out = (float*)d_out;

    char* ws = (char*)d_ws;
    const size_t SL = (size_t)4 * 8 * S_LEN * 64 * sizeof(short);  // 8 MiB per tensor
    // Lifetimes (stream-serialized): kp dies after repack, so ctx reuses its slab.
    short* qp    = (short*)(ws);            // proj -> attn
    short* kp    = (short*)(ws + SL);       // proj -> repack (dead after)
    short* ctx   = (short*)(ws + SL);       // attn -> outproj (reuses kp slab)
    short* vpT   = (short*)(ws + 2 * SL);   // proj -> repack
    short* kfrag = (short*)(ws + 3 * SL);   // repack -> attn
    short* vfrag = (short*)(ws + 4 * SL);   // repack -> attn
    short* WoT = (short*)(ws + 5 * SL);
    short* WqT = WoT + 512 * 512;
    short* WkT = WqT + 4096;
    short* WvT = WkT + 4096;

    prep_kernel<<<65, 256, 0, stream>>>(Wo, Wq, Wk, Wv, WoT, WqT, WkT, WvT);
    proj_kernel<<<dim3(16, 8, 12), 256, 0, stream>>>(q, k, v, bq, bk, bv,
                                                     WqT, WkT, WvT, qp, kp, vpT);
    repack_kernel<<<dim3(32, 8, 4), 128, 0, stream>>>(kp, vpT, kfrag, vfrag);
    attn_kernel<<<512, 256, 0, stream>>>(qp, kfrag, vfrag, vl, ctx);
    outproj_kernel<<<dim3(64, 8), 256, 0, stream>>>(ctx, WoT, bo, out);
}

// Round 5
// 165.277 us; speedup vs baseline: 1.1980x; 1.0910x over previous
//
#include <hip/hip_runtime.h>

#define S_LEN 2048
#define D_MODEL 512

typedef __attribute__((ext_vector_type(8))) short s8v;   // 8 x bf16 (4 VGPRs) MFMA A/B frag
typedef __attribute__((ext_vector_type(4))) float f4v;   // MFMA C/D frag
typedef __attribute__((ext_vector_type(4))) short s4v;
typedef __attribute__((ext_vector_type(4))) int   i4v;
typedef __attribute__((ext_vector_type(2))) int   i2v;

#define MFMA __builtin_amdgcn_mfma_f32_16x16x32_bf16

__device__ inline short f2bf(float x) {            // fp32 -> bf16 RNE
    union { float f; unsigned u; } v; v.f = x;
    unsigned r = v.u + 0x7fffu + ((v.u >> 16) & 1u);
    return (short)(r >> 16);
}
__device__ inline unsigned pack_bf2_trunc(float a, float b) { // truncating pack: 3 inst
    unsigned ua = __builtin_bit_cast(unsigned, a);
    unsigned ub = __builtin_bit_cast(unsigned, b);
    return (ua >> 16) | (ub & 0xffff0000u);
}

template <int C>
__device__ inline float dppf(float x) {            // DPP permute within 16-lane row
    int i = __builtin_bit_cast(int, x);
    i = __builtin_amdgcn_update_dpp(0, i, C, 0xF, 0xF, true);
    return __builtin_bit_cast(float, i);
}
__device__ inline float rowsum16(float x) {
    x += dppf<0xB1>(x);
    x += dppf<0x4E>(x);
    x += dppf<0x141>(x);
    x += dppf<0x140>(x);
    return x;
}

// async global->LDS, 16B per lane. LDS dest is wave-uniform base + lane*16
// (per-lane pointers computed as base + tid*16 satisfy this layout).
typedef const __attribute__((address_space(1))) void* gptr_t;
typedef __attribute__((address_space(3))) void* sptr_t;
__device__ inline void gload16(const void* g, void* s) {
    __builtin_amdgcn_global_load_lds((gptr_t)g, (sptr_t)s, 16, 0, 0);
}

// ---------------- prep: Wo transpose to bf16 (LDS-tiled, coalesced) ----------------
// Wq/Wk/Wv conversion moved into proj (per-block, L2-hot). Only WoT remains.
__global__ __launch_bounds__(256) void prep_kernel(
    const float* __restrict__ Wo, short* __restrict__ WoT)
{
    __shared__ short t[64 * 65];
    const int bi = (blockIdx.x >> 3) * 64;   // input-dim base (i)
    const int bj = (blockIdx.x & 7) * 64;    // output-dim base (o)
    const int c = threadIdx.x & 63, rr = threadIdx.x >> 6;
#pragma unroll
    for (int r = 0; r < 16; r++) {
        int i = r * 4 + rr;
        t[c * 65 + i] = f2bf(Wo[(size_t)(bi + i) * 512 + bj + c]);  // coalesced read
    }
    __syncthreads();
#pragma unroll
    for (int r = 0; r < 16; r++) {
        int o = r * 4 + rr;
        WoT[(size_t)(bj + o) * 512 + bi + c] = t[o * 65 + c];       // coalesced write
    }
}

// ---------------- fused projections+repack: qp [b][h][s][64], kfrag/vfrag tiles -------
// Each block covers 128 rows = exactly two 64-key frag tiles, so K/V frag
// reordering happens in-block: acc -> LDS (s,e) tile -> frag-order gather ->
// coalesced 1KB stores. Kills the separate repack kernel and the kp/vpT
// intermediates (32 MB of HBM traffic + a launch).
// LDS XOR swizzle: frag reads have 16 lanes reading rows spaced 4 apart; a
// padded stride can't be 16B-aligned AND conflict-free, so swizzle with key
// ((row>>2)&7) — the bits that vary across reading lanes — on write AND read.
__global__ __launch_bounds__(256) void proj_kernel(
    const float* __restrict__ q, const float* __restrict__ k, const float* __restrict__ v,
    const float* __restrict__ Wq, const float* __restrict__ Wk, const float* __restrict__ Wv,
    const float* __restrict__ bq, const float* __restrict__ bk, const float* __restrict__ bv,
    short* __restrict__ qp, short* __restrict__ kfrag, short* __restrict__ vfrag)
{
    __shared__ short sm[128 * 64];     // 16 KB union: wsm[64][64] -> ksm[128][64]/vsm[64][128]

    const int t = blockIdx.z >> 2;     // 0:q 1:k 2:v
    const int b = blockIdx.z & 3;
    const int h = blockIdx.y;
    const int qt = blockIdx.x;         // 16 row-tiles of 128
    const int w = threadIdx.x >> 6, lane = threadIdx.x & 63;
    const int l = lane & 15, qd = lane >> 4;

    const float* X    = (t == 0) ? q  : (t == 1) ? k  : v;
    const float* Wp   = (t == 0) ? Wq : (t == 1) ? Wk : Wv;
    const float* bias = (t == 0) ? bq : (t == 1) ? bk : bv;

    // ---- stage wsm[e][d] = W[d][e] (bf16, row-swizzled) ----
    {
        const int d = threadIdx.x >> 2, c4 = threadIdx.x & 3;   // 16 cols per thread
        const float* src = Wp + d * 64 + c4 * 16;
        f4v x0 = *(const f4v*)(src);
        f4v x1 = *(const f4v*)(src + 4);
        f4v x2 = *(const f4v*)(src + 8);
        f4v x3 = *(const f4v*)(src + 12);
        float xs[16] = {x0[0],x0[1],x0[2],x0[3], x1[0],x1[1],x1[2],x1[3],
                        x2[0],x2[1],x2[2],x2[3], x3[0],x3[1],x3[2],x3[3]};
#pragma unroll
        for (int j = 0; j < 16; j++) {
            int e = c4 * 16 + j;
            int sidx = (e * 64 + d) ^ (((e >> 2) & 7) << 3);
            sm[sidx] = f2bf(xs[j]);
        }
    }
    __syncthreads();

    const int s0 = qt * 128 + w * 32;

    // A frags direct from global fp32, converted
    s8v a[2][2];
#pragma unroll
    for (int mt = 0; mt < 2; mt++)
#pragma unroll
        for (int kk = 0; kk < 2; kk++) {
            const float* p = X + (size_t)(b * S_LEN + s0 + mt * 16 + l) * 512 + h * 64 + kk * 32 + qd * 8;
            f4v x0 = *(const f4v*)p;
            f4v x1 = *(const f4v*)(p + 4);
            s8v fr;
            fr[0] = f2bf(x0[0]); fr[1] = f2bf(x0[1]); fr[2] = f2bf(x0[2]); fr[3] = f2bf(x0[3]);
            fr[4] = f2bf(x1[0]); fr[5] = f2bf(x1[1]); fr[6] = f2bf(x1[2]); fr[7] = f2bf(x1[3]);
            a[mt][kk] = fr;
        }
    // B frags from wsm: q/k use e = 4*l + nt, v uses e = nt*16 + l
    s8v wf[4][2];
#pragma unroll
    for (int nt = 0; nt < 4; nt++) {
        int wrow = (t < 2) ? (4 * l + nt) : (nt * 16 + l);
        int key = ((wrow >> 2) & 7) << 3;
#pragma unroll
        for (int kk = 0; kk < 2; kk++)
            wf[nt][kk] = *(const s8v*)(sm + ((wrow * 64 + kk * 32 + qd * 8) ^ key));
    }

    const f4v fz = {0.f, 0.f, 0.f, 0.f};
    f4v acc[2][4];
#pragma unroll
    for (int mt = 0; mt < 2; mt++)
#pragma unroll
        for (int nt = 0; nt < 4; nt++) acc[mt][nt] = fz;

#pragma unroll
    for (int kk = 0; kk < 2; kk++)
#pragma unroll
        for (int nt = 0; nt < 4; nt++)
#pragma unroll
            for (int mt = 0; mt < 2; mt++)
                acc[mt][nt] = MFMA(a[mt][kk], wf[nt][kk], acc[mt][nt], 0, 0, 0);

    // fold softmax scale * log2(e) into Q so attention uses exp2 directly
    const float SC = 0.125f * 1.442695041f;

    if (t == 0) {
        float bbs[4];
#pragma unroll
        for (int nt = 0; nt < 4; nt++) bbs[nt] = bias[4 * l + nt];
#pragma unroll
        for (int mt = 0; mt < 2; mt++)
#pragma unroll
            for (int r = 0; r < 4; r++) {
                int s = s0 + mt * 16 + qd * 4 + r;
                s4v pk;
#pragma unroll
                for (int nt = 0; nt < 4; nt++)
                    pk[nt] = f2bf((acc[mt][nt][r] + bbs[nt]) * SC);
                *(s4v*)(qp + ((size_t)(b * 8 + h) * S_LEN + s) * 64 + 4 * l) = pk;
            }
        return;
    }

    __syncthreads();   // all wf reads done before sm is overwritten

    if (t == 1) {
        // ksm[s_local][e], stride 64, swizzle key (s_local>>2)&7
        float bbs[4];
#pragma unroll
        for (int nt = 0; nt < 4; nt++) bbs[nt] = bias[4 * l + nt];
#pragma unroll
        for (int mt = 0; mt < 2; mt++)
#pragma unroll
            for (int r = 0; r < 4; r++) {
                int sl = w * 32 + mt * 16 + qd * 4 + r;
                s4v pk;
#pragma unroll
                for (int nt = 0; nt < 4; nt++) pk[nt] = f2bf(acc[mt][nt][r] + bbs[nt]);
                int sidx = (sl * 64 + 4 * l) ^ (((sl >> 2) & 7) << 3);
                *(s4v*)(sm + sidx) = pk;
            }
    } else {
        // vsm[e][s_local], stride 128, swizzle key (e>>2)&7
#pragma unroll
        for (int nt = 0; nt < 4; nt++) {
            float bb = bias[nt * 16 + l];
            int e = nt * 16 + l;
            int key = ((e >> 2) & 7) << 3;
#pragma unroll
            for (int mt = 0; mt < 2; mt++) {
                s4v pk;
#pragma unroll
                for (int r = 0; r < 4; r++) pk[r] = f2bf(acc[mt][nt][r] + bb);
                int sidx = (e * 128 + w * 32 + mt * 16 + qd * 4) ^ key;
                *(s4v*)(sm + sidx) = pk;
            }
        }
    }
    __syncthreads();

    // ---- frag-order gather + coalesced stores (2 tiles x 8 chunks x 1KB) ----
    short* dst = (t == 1) ? kfrag : vfrag;
    const size_t obase0 = ((size_t)(b * 8 + h) * 32 + qt * 2) * 4096;
    const int f = threadIdx.x & 63, cp = threadIdx.x >> 6;
    const int fl = f & 15, fq = f >> 4;
#pragma unroll
    for (int tt = 0; tt < 2; tt++)
#pragma unroll
        for (int ci = 0; ci < 2; ci++) {
            int c = cp + ci * 4;
            int n2 = c >> 1, kk = c & 1;
            int sidx;
            if (t == 1) {
                int sl = tt * 64 + 4 * fl + n2;
                sidx = (sl * 64 + kk * 32 + fq * 8) ^ (((sl >> 2) & 7) << 3);
            } else {
                int e = 4 * fl + n2;
                sidx = (e * 128 + tt * 64 + kk * 32 + fq * 8) ^ (((e >> 2) & 7) << 3);
            }
            s8v x = *(const s8v*)(sm + sidx);
            *(s8v*)(dst + obase0 + tt * 4096 + c * 512 + f * 8) = x;
        }
}

// ---------------- flash attention v8: v6 structure + vlen pairing + setprio -----------
// 4 waves/block, LDS-staged K/V (global_load_lds, dbuf), b^=3 pairing for vlen
// balance, setprio around MFMA clusters. Best measured config (<41us).
__global__ __launch_bounds__(256, 3) void attn_kernel(
    const short* __restrict__ qp, const short* __restrict__ kfrag,
    const short* __restrict__ vfrag,
    const int* __restrict__ valid_lens, short* __restrict__ ctx)
{
    __shared__ alignas(16) short kbuf[2][4096];   // 8 KB K tile, frag order, dbuf
    __shared__ alignas(16) short vbuf[2][4096];   // 8 KB V tile
    __shared__ alignas(16) short lP[4][32 * 72];  // per-wave P scratch, stride 72

    const int gid = blockIdx.x;
    const int h  = gid & 7;            // gid%8 -> XCD heuristic for K/V L2 locality
    int b        = (gid >> 3) & 3;
    const int qt = gid >> 5;           // 0..15, 128 rows per block
    b ^= 3 * ((gid >> 8) & 1);         // pair (b, b^3) batches on each CU: vlen balance
    const int w = threadIdx.x >> 6, lane = threadIdx.x & 63;
    const int l = lane & 15, qd = lane >> 4;
    const int vlen = valid_lens[b];
    const int ntiles = (vlen + 63) >> 6;   // skip fully-masked tiles: exp==0 exactly

    const int bh = b * 8 + h;
    const short* Qs = qp + (size_t)bh * S_LEN * 64;
    const short* Kf = kfrag + (size_t)bh * 32 * 4096;
    const short* Vf = vfrag + (size_t)bh * 32 * 4096;

    const int s0 = qt * 128 + w * 32;
    s8v qf[2][2];
#pragma unroll
    for (int mt = 0; mt < 2; mt++)
#pragma unroll
        for (int kk = 0; kk < 2; kk++)
            qf[mt][kk] = *(const s8v*)(Qs + (size_t)(s0 + mt * 16 + l) * 64 + kk * 32 + qd * 8);

    const f4v fz = {0.f, 0.f, 0.f, 0.f};
    f4v O[2][4];
    float lsum[2][4];
#pragma unroll
    for (int mt = 0; mt < 2; mt++)
#pragma unroll
        for (int r = 0; r < 4; r++) lsum[mt][r] = 0.f;
#pragma unroll
    for (int mt = 0; mt < 2; mt++)
#pragma unroll
        for (int ne = 0; ne < 4; ne++) O[mt][ne] = fz;

    short* lPw = lP[w];
    const int toff = threadIdx.x * 8;  // 16B per thread; per-wave-linear LDS dest

    // prologue: stage tile 0 into buffer 0 (4KB per round, 2 rounds per tensor)
    gload16(Kf + toff,        &kbuf[0][toff]);
    gload16(Kf + 2048 + toff, &kbuf[0][2048 + toff]);
    gload16(Vf + toff,        &vbuf[0][toff]);
    gload16(Vf + 2048 + toff, &vbuf[0][2048 + toff]);
    __syncthreads();   // compiler emits vmcnt(0) drain before s_barrier

    for (int kb = 0; kb < ntiles; kb++) {
        const int cur = kb & 1;
        // issue next-tile prefetch FIRST so it flies under this tile's compute
        if (kb + 1 < ntiles) {
            const short* Ks = Kf + (size_t)(kb + 1) * 4096;
            const short* Vs = Vf + (size_t)(kb + 1) * 4096;
            gload16(Ks + toff,        &kbuf[cur ^ 1][toff]);
            gload16(Ks + 2048 + toff, &kbuf[cur ^ 1][2048 + toff]);
            gload16(Vs + toff,        &vbuf[cur ^ 1][toff]);
            gload16(Vs + 2048 + toff, &vbuf[cur ^ 1][2048 + toff]);
        }

        // K fragments from LDS: contiguous 1KB per chunk, conflict-free
        const short* Kb = &kbuf[cur][lane * 8];
        s8v kf[4][2];
#pragma unroll
        for (int nt = 0; nt < 4; nt++)
#pragma unroll
            for (int kk = 0; kk < 2; kk++)
                kf[nt][kk] = *(const s8v*)(Kb + (nt * 2 + kk) * 512);

        f4v sf[2][4];
#pragma unroll
        for (int mt = 0; mt < 2; mt++)
#pragma unroll
            for (int nt = 0; nt < 4; nt++) sf[mt][nt] = fz;
        __builtin_amdgcn_s_setprio(1);
#pragma unroll
        for (int nt = 0; nt < 4; nt++)
#pragma unroll
            for (int mt = 0; mt < 2; mt++) {
                sf[mt][nt] = MFMA(qf[mt][0], kf[nt][0], sf[mt][nt], 0, 0, 0);
                sf[mt][nt] = MFMA(qf[mt][1], kf[nt][1], sf[mt][nt], 0, 0, 0);
            }
        __builtin_amdgcn_s_setprio(0);

        // V fragments (issued here so QK+softmax covers their latency)
        const short* Vb = &vbuf[cur][lane * 8];
        s8v vf[4][2];
#pragma unroll
        for (int ne = 0; ne < 4; ne++)
#pragma unroll
            for (int kk = 0; kk < 2; kk++)
                vf[ne][kk] = *(const s8v*)(Vb + (ne * 2 + kk) * 512);

        // boundary-tile key mask (key at (nt,l) = kb*64 + 4*l + nt)
        if (kb == ntiles - 1 && (vlen & 63)) {
            int rem = vlen - kb * 64;
#pragma unroll
            for (int nt = 0; nt < 4; nt++)
                if (4 * l + nt >= rem) {
#pragma unroll
                    for (int mt = 0; mt < 2; mt++)
#pragma unroll
                        for (int r = 0; r < 4; r++) sf[mt][nt][r] = -1e30f;
                }
        }

        // softmax, no max subtraction; truncating bf16 pack; one ds_write_b64/row-reg
#pragma unroll
        for (int mt = 0; mt < 2; mt++)
#pragma unroll
            for (int r = 0; r < 4; r++) {
                float p0 = __builtin_amdgcn_exp2f(sf[mt][0][r]);
                float p1 = __builtin_amdgcn_exp2f(sf[mt][1][r]);
                float p2 = __builtin_amdgcn_exp2f(sf[mt][2][r]);
                float p3 = __builtin_amdgcn_exp2f(sf[mt][3][r]);
                lsum[mt][r] += (p0 + p1) + (p2 + p3);
                i2v pk;
                pk[0] = (int)pack_bf2_trunc(p0, p1);
                pk[1] = (int)pack_bf2_trunc(p2, p3);
                *(i2v*)(lPw + (mt * 16 + qd * 4 + r) * 72 + 4 * l) = pk;
            }

        // O += P V  (A-frags from wave-private LDS; no barrier needed)
        s8v pa[2][2];
#pragma unroll
        for (int mt = 0; mt < 2; mt++)
#pragma unroll
            for (int kk = 0; kk < 2; kk++)
                pa[mt][kk] = *(const s8v*)(lPw + (mt * 16 + l) * 72 + kk * 32 + qd * 8);
        __builtin_amdgcn_s_setprio(1);
#pragma unroll
        for (int ne = 0; ne < 4; ne++)
#pragma unroll
            for (int mt = 0; mt < 2; mt++) {
                O[mt][ne] = MFMA(pa[mt][0], vf[ne][0], O[mt][ne], 0, 0, 0);
                O[mt][ne] = MFMA(pa[mt][1], vf[ne][1], O[mt][ne], 0, 0, 0);
            }
        __builtin_amdgcn_s_setprio(0);

        // all waves done reading buf[cur]; prefetch into buf[cur^1] drained here
        __syncthreads();
    }

    // normalize + write ctx[b][s][h*64 + e] (bf16), packed 8B stores (e = 4*l+ne)
#pragma unroll
    for (int mt = 0; mt < 2; mt++)
#pragma unroll
        for (int r = 0; r < 4; r++) {
            float inv = 1.0f / rowsum16(lsum[mt][r]);
            int s = s0 + mt * 16 + qd * 4 + r;
            s4v pk;
#pragma unroll
            for (int ne = 0; ne < 4; ne++) pk[ne] = f2bf(O[mt][ne][r] * inv);
            *(s4v*)(ctx + ((size_t)(b * S_LEN + s)) * 512 + h * 64 + 4 * l) = pk;
        }
}

// ---------------- output projection: [8192,512] = ctx @ Wo + bo ----------------
__global__ __launch_bounds__(256) void outproj_kernel(
    const short* __restrict__ ctx, const short* __restrict__ WoT,
    const float* __restrict__ bo, float* __restrict__ out)
{
    __shared__ short lB[64 * 520];   // Wo^T tile, padded stride (kills 1024B-stride alias)
    __shared__ short lA[128 * 40];   // A k-slab, padded stride 40 shorts (80B)

    const int rb = blockIdx.x * 128;
    const int nb = blockIdx.y * 64;
    const int w = threadIdx.x >> 6, lane = threadIdx.x & 63;
    const int l = lane & 15, qd = lane >> 4;

    {   // stage B tile once: 64 rows x 512
        int n = threadIdx.x >> 2, c0 = threadIdx.x & 3;
#pragma unroll
        for (int i = 0; i < 16; i++) {
            int g = i * 4 + c0;  // 64 granules of 8 shorts
            i4v x = *(const i4v*)(WoT + (size_t)(nb + n) * 512 + g * 8);
            *(i4v*)(lB + n * 520 + g * 8) = x;
        }
    }
    __syncthreads();

    const f4v fz = {0.f, 0.f, 0.f, 0.f};
    f4v acc[2][4];
#pragma unroll
    for (int mt = 0; mt < 2; mt++)
#pragma unroll
        for (int nt = 0; nt < 4; nt++) acc[mt][nt] = fz;

    for (int ko = 0; ko < 16; ko++) {
        {   // stage A slab 128x32
            int r = threadIdx.x >> 1, hp = threadIdx.x & 1;
            const short* src = ctx + (size_t)(rb + r) * 512 + ko * 32 + hp * 16;
            i4v x0 = *(const i4v*)src;
            i4v x1 = *(const i4v*)(src + 8);
            *(i4v*)(lA + r * 40 + hp * 16) = x0;
            *(i4v*)(lA + r * 40 + hp * 16 + 8) = x1;
        }
        __syncthreads();
        s8v af[2];
#pragma unroll
        for (int mt = 0; mt < 2; mt++)
            af[mt] = *(const s8v*)(lA + (w * 32 + mt * 16 + l) * 40 + qd * 8);
#pragma unroll
        for (int nt = 0; nt < 4; nt++) {
            s8v bfr = *(const s8v*)(lB + (nt * 16 + l) * 520 + ko * 32 + qd * 8);
#pragma unroll
            for (int mt = 0; mt < 2; mt++)
                acc[mt][nt] = MFMA(af[mt], bfr, acc[mt][nt], 0, 0, 0);
        }
        __syncthreads();
    }

#pragma unroll
    for (int nt = 0; nt < 4; nt++) {
        float bias = bo[nb + nt * 16 + l];
#pragma unroll
        for (int mt = 0; mt < 2; mt++)
#pragma unroll
            for (int r = 0; r < 4; r++) {
                int row = rb + w * 32 + mt * 16 + qd * 4 + r;
                out[(size_t)row * 512 + nb + nt * 16 + l] = acc[mt][nt][r] + bias;
            }
    }
}

extern "C" void kernel_launch(void* const* d_in, const int* in_sizes, int n_in,
                              void* d_out, int out_size, void* d_ws, size_t ws_size,
                              hipStream_t stream)
{
    const float* q  = (const float*)d_in[0];
    const float* k  = (const float*)d_in[1];
    const float* v  = (const float*)d_in[2];
    const float* Wq = (const float*)d_in[3];
    const float* bq = (const float*)d_in[4];
    const float* Wk = (const float*)d_in[5];
    const float* bk = (const float*)d_in[6];
    const float* Wv = (const float*)d_in[7];
    const float* bv = (const float*)d_in[8];
    const float* Wo = (const float*)d_in[9];
    const float* bo = (const float*)d_in[10];
    const int*   vl = (const int*)d_in[11];
    float* out = (float*)d_out;

    char* ws = (char*)d_ws;
    const size_t SL = (size_t)4 * 8 * S_LEN * 64 * sizeof(short);  // 8 MiB per tensor
    short* qp    = (short*)(ws);            // proj -> attn
    short* ctx   = (short*)(ws + SL);       // attn -> outproj
    short* kfrag = (short*)(ws + 2 * SL);   // proj -> attn
    short* vfrag = (short*)(ws + 3 * SL);   // proj -> attn
    short* WoT   = (short*)(ws + 4 * SL);   // prep -> outproj

    prep_kernel<<<64, 256, 0, stream>>>(Wo, WoT);
    proj_kernel<<<dim3(16, 8, 12), 256, 0, stream>>>(q, k, v, Wq, Wk, Wv,
                                                     bq, bk, bv, qp, kfrag, vfrag);
    attn_kernel<<<512, 256, 0, stream>>>(qp, kfrag, vfrag, vl, ctx);
    outproj_kernel<<<dim3(64, 8), 256, 0, stream>>>(ctx, WoT, bo, out);
}